// Round 9
// baseline (219.111 us; speedup 1.0000x reference)
//
#include <hip/hip_runtime.h>

// 2-layer GCN, R21: quad-gather + L2-resident half-plane, STRUCTURAL
// PARITY with R16 (the experiment R17 failed to run cleanly).
//   R20 null: nt edge loads changed nothing -> the 6.4MB y1 plane
//   self-thrashes L2. R17's "residency doesn't matter" was confounded by
//   2x window duplication + 2x epilogues. R21 isolates residency:
//   -> k_build: 512-key sort (src_half, dst) -> cp0/cp1 (R17's verified)
//   -> k_fuse2: block=(bucket, src-half), 1024 thr = 256 nodes x 4 lanes;
//      each block copies its half-range window ONCE (total = E, R16
//      parity); quad-gather (1 inst + 1 line-visit/edge) from one 3.2MB
//      half-plane; hs=bx&1 -> half0 on even XCDs, half1 on odd (each L2
//      holds one half). One pooling epilogue per block (2/bucket = R16
//      parity).
//   -> k_fuse1: dual-range pair-gather (R17 form).
//
// Standing lessons: R1/R2 no scattered-4B stores / hot global atomics; R4
// no single-block stages; R6 register accumulation; R10 no cooperative
// launch; R13 atomic segment reservation; R14 occupancy is not the gather
// lever; R15 no dependent load pairs; R16 quad-gather is the right shape;
// R18 scatter needs big EPB; R20 edge-stream nt-loads are a no-op.

constexpr int EPB = 16384;         // edges per scatter block
constexpr int BSH = 8;             // 256 nodes per fine bucket
constexpr int BKTN = 1 << BSH;
constexpr int CAP = 10240;         // per-bucket slot capacity (max ~8.6K here)
constexpr int CAPC = 8704;         // fuse1 LDS window (34KB)
constexpr int CAPF = 5376;         // fuse2 half-range window (21.5KB)

typedef int vint4 __attribute__((ext_vector_type(4)));  // native 16B vector

__device__ inline unsigned short f2bf(float x) {
  unsigned u = __float_as_uint(x);
  u += 0x7FFF + ((u >> 16) & 1);   // round-to-nearest-even
  return (unsigned short)(u >> 16);
}
__device__ inline float bf2f(unsigned short h) {
  return __uint_as_float((unsigned)h << 16);
}
__device__ inline unsigned pk(float a, float b) {
  return (unsigned)f2bf(a) | ((unsigned)f2bf(b) << 16);
}
__device__ __forceinline__ void add8(float* acc, uint4 v) {
  acc[0] += bf2f(v.x & 0xFFFF); acc[1] += bf2f(v.x >> 16);
  acc[2] += bf2f(v.y & 0xFFFF); acc[3] += bf2f(v.y >> 16);
  acc[4] += bf2f(v.z & 0xFFFF); acc[5] += bf2f(v.z >> 16);
  acc[6] += bf2f(v.w & 0xFFFF); acc[7] += bf2f(v.w >> 16);
}

// fuse1 gather: 2 lanes per 32B row, depth-4 + prefetch pipeline
__device__ __forceinline__ void gather8(const unsigned short* __restrict__ base,
                                        const int* list, int st, int dg,
                                        float acc[8]) {
  int j = 0;
  if (dg >= 8) {
    int r0 = list[st], r1 = list[st + 1], r2 = list[st + 2], r3 = list[st + 3];
    uint4 v0 = *(const uint4*)(base + (size_t)r0 * 16);
    uint4 v1 = *(const uint4*)(base + (size_t)r1 * 16);
    uint4 v2 = *(const uint4*)(base + (size_t)r2 * 16);
    uint4 v3 = *(const uint4*)(base + (size_t)r3 * 16);
    for (j = 4; j + 4 <= dg; j += 4) {
      int s0 = list[st + j], s1 = list[st + j + 1];
      int s2 = list[st + j + 2], s3 = list[st + j + 3];
      uint4 w0 = *(const uint4*)(base + (size_t)s0 * 16);
      uint4 w1 = *(const uint4*)(base + (size_t)s1 * 16);
      uint4 w2 = *(const uint4*)(base + (size_t)s2 * 16);
      uint4 w3 = *(const uint4*)(base + (size_t)s3 * 16);
      add8(acc, v0); add8(acc, v1); add8(acc, v2); add8(acc, v3);
      v0 = w0; v1 = w1; v2 = w2; v3 = w3;
    }
    add8(acc, v0); add8(acc, v1); add8(acc, v2); add8(acc, v3);
  }
  for (; j < dg; ++j)
    add8(acc, *(const uint4*)(base + (size_t)list[st + j] * 16));
}

// fuse2 quad gather: 4 lanes cover one 64B y1 row per edge (one vmem
// instruction per 16 edges); base pre-offset by qf*8 shorts
__device__ __forceinline__ void gather_quad(const unsigned short* __restrict__ base,
                                            const int* list, int st, int dg,
                                            float acc[8]) {
  int j = 0;
  if (dg >= 8) {
    int r0 = list[st], r1 = list[st + 1], r2 = list[st + 2], r3 = list[st + 3];
    uint4 v0 = *(const uint4*)(base + (size_t)r0 * 32);
    uint4 v1 = *(const uint4*)(base + (size_t)r1 * 32);
    uint4 v2 = *(const uint4*)(base + (size_t)r2 * 32);
    uint4 v3 = *(const uint4*)(base + (size_t)r3 * 32);
    for (j = 4; j + 4 <= dg; j += 4) {
      int s0 = list[st + j], s1 = list[st + j + 1];
      int s2 = list[st + j + 2], s3 = list[st + j + 3];
      uint4 w0 = *(const uint4*)(base + (size_t)s0 * 32);
      uint4 w1 = *(const uint4*)(base + (size_t)s1 * 32);
      uint4 w2 = *(const uint4*)(base + (size_t)s2 * 32);
      uint4 w3 = *(const uint4*)(base + (size_t)s3 * 32);
      add8(acc, v0); add8(acc, v1); add8(acc, v2); add8(acc, v3);
      v0 = w0; v1 = w1; v2 = w2; v3 = w3;
    }
    add8(acc, v0); add8(acc, v1); add8(acc, v2); add8(acc, v3);
  }
  for (; j < dg; ++j)
    add8(acc, *(const uint4*)(base + (size_t)list[st + j] * 32));
}

// coalesced window copy global->LDS, nt loads (edge list is one-shot)
__device__ __forceinline__ void copy_window(int* list, const int* __restrict__ src,
                                            int n, int tid, int nthr) {
  const vint4* s4 = (const vint4*)src;
  vint4* d4 = (vint4*)list;
  int n4 = n >> 2;
  for (int i = tid; i < n4; i += nthr) d4[i] = __builtin_nontemporal_load(s4 + i);
  for (int i = (n4 << 2) + tid; i < n; i += nthr)
    list[i] = __builtin_nontemporal_load(src + i);
}

// XCD swizzle: adjacent edge windows handled by same-XCD blocks (blk%8 heur.)
__device__ __forceinline__ int swz(int b, int nblkp) {
  return (b & 7) * (nblkp >> 3) + (b >> 3);
}

// scatter: in-LDS counting sort of this block's 16K edges; per-bucket
// global segment reserved via ONE atomicAdd on cursor[b]; coalesced flush
// into padded staging[b*CAP + base ...].
__global__ __launch_bounds__(1024) void k_scatter(const int* __restrict__ row,
                                                  const int* __restrict__ col, int E,
                                                  int nbkt, int nblkp,
                                                  int* __restrict__ cursor,
                                                  int* __restrict__ staging) {
  __shared__ int sbuf[EPB];
  __shared__ int cnt[512], sc[512], cur[512], gbase[512];
  int tid = threadIdx.x;
  int lane = tid & 63, wv = tid >> 6;
  int blk = swz(blockIdx.x, nblkp);
  if (tid < 512) cnt[tid] = 0;
  __syncthreads();
  int e0 = blk * EPB, e1 = min(E, e0 + EPB);
  for (int e = e0 + tid; e < e1; e += 1024)
    atomicAdd(&cnt[col[e] >> BSH], 1);
  __syncthreads();
  if (tid < 512) {
    int c = cnt[tid];
    sc[tid] = c;
    gbase[tid] = c ? atomicAdd(&cursor[tid], c) : 0;  // segment reservation
  }
  __syncthreads();
  for (int o = 1; o < 512; o <<= 1) {
    int u = (tid < 512 && tid >= o) ? sc[tid - o] : 0;
    __syncthreads();
    if (tid < 512) sc[tid] += u;
    __syncthreads();
  }
  if (tid < 512) { int st = sc[tid] - cnt[tid]; sc[tid] = st; cur[tid] = st; }
  __syncthreads();
  for (int e = e0 + tid; e < e1; e += 1024) {
    int c = col[e];
    int b = c >> BSH;
    int pos = atomicAdd(&cur[b], 1);
    sbuf[pos] = (row[e] << BSH) | (c & (BKTN - 1));
  }
  __syncthreads();
  for (int b = wv; b < nbkt; b += 16) {
    int lbeg = sc[b], lcnt = cnt[b];
    int gb = gbase[b];
    int lim = CAP - gb;                 // overflow guard (never hit at scale)
    if (lcnt > lim) lcnt = lim > 0 ? lim : 0;
    int g = b * CAP + gb;
    for (int j = lane; j < lcnt; j += 64)
      staging[g + j] = sbuf[lbeg + j];
  }
}

// per fine bucket: 9-bit-key (src_half, dst_local) counting sort ->
// cp0/cp1/endp + fused emb transform; LDS fill sorted; COALESCED flush.
__global__ __launch_bounds__(512) void k_build(const int* __restrict__ staging,
                                               const int* __restrict__ cursor,
                                               const int* __restrict__ x_ids,
                                               const float* __restrict__ emb,
                                               int N, int Nh, int nbkt,
                                               int* __restrict__ cp0,
                                               int* __restrict__ cp1,
                                               int* __restrict__ endp,
                                               float* __restrict__ dinv,
                                               unsigned short* __restrict__ ag1,
                                               int* __restrict__ edge_row) {
  __shared__ int list[CAP];
  __shared__ int cnt[512], sc[512], lcur[512];
  int tid = threadIdx.x, b = blockIdx.x;
  int beg = b * CAP;
  int total = min(cursor[b], CAP);
  int end = beg + total;
  cnt[tid] = 0;
  __syncthreads();
  for (int i = beg + tid; i < end; i += 512) {
    int p = staging[i];
    int key = ((p >> BSH) >= Nh ? 256 : 0) | (p & (BKTN - 1));
    atomicAdd(&cnt[key], 1);
  }
  __syncthreads();
  sc[tid] = cnt[tid];
  __syncthreads();
  for (int o = 1; o < 512; o <<= 1) {
    int u = (tid >= o) ? sc[tid - o] : 0;
    __syncthreads();
    sc[tid] += u;
    __syncthreads();
  }
  {
    int excl = sc[tid] - cnt[tid];
    sc[tid] = excl;
    lcur[tid] = excl;
    if (tid < 256) cp0[(b << BSH) + tid] = beg + excl;
    else cp1[(b << BSH) + tid - 256] = beg + excl;
  }
  if (tid == 0) endp[b] = end;
  __syncthreads();
  for (int i = beg + tid; i < end; i += 512) {
    int p = staging[i];
    int key = ((p >> BSH) >= Nh ? 256 : 0) | (p & (BKTN - 1));
    list[atomicAdd(&lcur[key], 1)] = p >> BSH;
  }
  __syncthreads();
  for (int i = beg + tid; i < end; i += 512)
    edge_row[i] = list[i - beg];
  // fused embedding transform: 2 lanes/node x 8 feats
  int nloc = tid >> 1, half = tid & 1;
  int node = (b << BSH) + nloc;
  if (node < N) {
    int deg = cnt[nloc] + cnt[256 + nloc];
    float d = rsqrtf((float)(deg + 1));  // +1 self-loop
    if (half == 0) dinv[node] = d;
    const float* er = emb + (size_t)x_ids[node] * 16 + half * 8;
    float4 e0 = *(const float4*)(er);
    float4 e1 = *(const float4*)(er + 4);
    uint4 o;
    o.x = pk(e0.x * d, e0.y * d); o.y = pk(e0.z * d, e0.w * d);
    o.z = pk(e1.x * d, e1.y * d); o.w = pk(e1.z * d, e1.w * d);
    *(uint4*)(ag1 + (size_t)node * 16 + half * 8) = o;
  }
}

// layer 1: window copy -> LDS; pipelined gather over BOTH src-half ranges;
// fused 16->32 GEMV/ReLU -> unified y1 [N][32] bf16 (64B rows).
__global__ __launch_bounds__(512) void k_fuse1(const unsigned short* __restrict__ ag1,
                                               const int* __restrict__ edge_row,
                                               const int* __restrict__ cp0,
                                               const int* __restrict__ cp1,
                                               const int* __restrict__ endp,
                                               const float* __restrict__ dinv,
                                               const float* __restrict__ W1,
                                               const float* __restrict__ b1, int N,
                                               unsigned short* __restrict__ y1) {
  __shared__ int list[CAPC];
  __shared__ float W[512];
  __shared__ float bb[32];
  int tid = threadIdx.x, b = blockIdx.x;
  W[tid] = W1[tid];
  if (tid < 32) bb[tid] = b1[tid];
  int nloc = tid >> 1, half = tid & 1;
  int node = (b << BSH) + nloc;
  bool valid = node < N;
  int beg = b * CAP;
  int end = endp[b];
  int h1beg = cp1[b << BSH];           // end of half0 region
  int s0 = 0, e0 = 0, s1 = 0, e1 = 0;
  float acc[8];
  if (valid) {
    s0 = cp0[node];
    e0 = (nloc == BKTN - 1) ? h1beg : cp0[node + 1];
    s1 = cp1[node];
    e1 = (nloc == BKTN - 1) ? end : cp1[node + 1];
    uint4 v = *(const uint4*)(ag1 + (size_t)node * 16 + half * 8);
    acc[0] = bf2f(v.x & 0xFFFF); acc[1] = bf2f(v.x >> 16);
    acc[2] = bf2f(v.y & 0xFFFF); acc[3] = bf2f(v.y >> 16);
    acc[4] = bf2f(v.z & 0xFFFF); acc[5] = bf2f(v.z >> 16);
    acc[6] = bf2f(v.w & 0xFFFF); acc[7] = bf2f(v.w >> 16);
  } else {
#pragma unroll
    for (int k = 0; k < 8; ++k) acc[k] = 0.f;
  }
  for (int cbeg = beg; cbeg < end; cbeg += CAPC) {
    int cend = min(end, cbeg + CAPC);
    __syncthreads();
    copy_window(list, edge_row + cbeg, cend - cbeg, tid, 512);
    __syncthreads();
    if (valid) {
      int st = max(s0, cbeg), en = min(e0, cend);
      if (en > st) gather8(ag1 + half * 8, list, st - cbeg, en - st, acc);
      st = max(s1, cbeg); en = min(e1, cend);
      if (en > st) gather8(ag1 + half * 8, list, st - cbeg, en - st, acc);
    }
  }
  if (!valid) return;
  float d = dinv[node];
  float sx[8], xo[8];
#pragma unroll
  for (int k = 0; k < 8; ++k) sx[k] = acc[k] * d;
#pragma unroll
  for (int k = 0; k < 8; ++k) xo[k] = __shfl_xor(sx[k], 1);
  float x[16];
  if (half == 0) {
#pragma unroll
    for (int k = 0; k < 8; ++k) { x[k] = sx[k]; x[8 + k] = xo[k]; }
  } else {
#pragma unroll
    for (int k = 0; k < 8; ++k) { x[k] = xo[k]; x[8 + k] = sx[k]; }
  }
  int j0 = half * 16;
  float a[16];
#pragma unroll
  for (int j = 0; j < 16; ++j) a[j] = bb[j0 + j];
#pragma unroll
  for (int k = 0; k < 16; ++k) {
    float xv = x[k];
#pragma unroll
    for (int j = 0; j < 16; ++j) a[j] += xv * W[k * 32 + j0 + j];
  }
#pragma unroll
  for (int j = 0; j < 16; ++j) a[j] = fmaxf(a[j], 0.f) * d;
  uint4 o0 = {pk(a[0], a[1]), pk(a[2], a[3]), pk(a[4], a[5]), pk(a[6], a[7])};
  uint4 o1 = {pk(a[8], a[9]), pk(a[10], a[11]), pk(a[12], a[13]), pk(a[14], a[15])};
  unsigned short* yp = y1 + (size_t)node * 32 + half * 16;
  *(uint4*)(yp) = o0;
  *(uint4*)(yp + 8) = o1;
}

// layer 2: quad-gather, L2-resident half-plane, R16 structural parity.
// block=(bucket, src-half): 1024 thr = 256 nodes x 4 lanes. Each block
// copies its half-range ONCE; hs=bx&1 -> half0 on even XCDs, half1 odd.
// One pooling epilogue per block (2/bucket).
__global__ __launch_bounds__(1024) void k_fuse2(const unsigned short* __restrict__ y1,
                                                const int* __restrict__ edge_row,
                                                const int* __restrict__ cp0,
                                                const int* __restrict__ cp1,
                                                const int* __restrict__ endp,
                                                const float* __restrict__ dinv,
                                                const int* __restrict__ batch,
                                                int N, int Nh, int nbkt,
                                                float* __restrict__ P) {
  __shared__ int list[CAPF];
  __shared__ float pool[8 * 32];
  int bx = blockIdx.x;
  int hs = bx & 1;                    // src half; even XCDs get hs=0
  int b = bx >> 1;
  int tid = threadIdx.x;
  int nloc = tid >> 2, qf = tid & 3;
  int node = (b << BSH) + nloc;
  bool valid = node < N;
  int end = endp[b];
  int h1beg = cp1[b << BSH];
  int rbeg = hs ? h1beg : b * CAP;
  int rend = hs ? end : h1beg;
  int ms = 0, me = 0;
  float acc[8];
  if (valid) {
    if (hs == 0) {
      ms = cp0[node];
      me = (nloc == BKTN - 1) ? h1beg : cp0[node + 1];
    } else {
      ms = cp1[node];
      me = (nloc == BKTN - 1) ? end : cp1[node + 1];
    }
  }
  // self term once, in the pass owning the node's own src half
  if (valid && ((node >= Nh) ? 1 : 0) == hs) {
    uint4 v = *(const uint4*)(y1 + (size_t)node * 32 + qf * 8);
    acc[0] = bf2f(v.x & 0xFFFF); acc[1] = bf2f(v.x >> 16);
    acc[2] = bf2f(v.y & 0xFFFF); acc[3] = bf2f(v.y >> 16);
    acc[4] = bf2f(v.z & 0xFFFF); acc[5] = bf2f(v.z >> 16);
    acc[6] = bf2f(v.w & 0xFFFF); acc[7] = bf2f(v.w >> 16);
  } else {
#pragma unroll
    for (int k = 0; k < 8; ++k) acc[k] = 0.f;
  }
  for (int cbeg = rbeg; cbeg < rend; cbeg += CAPF) {
    int cend = min(rend, cbeg + CAPF);
    __syncthreads();
    copy_window(list, edge_row + cbeg, cend - cbeg, tid, 1024);
    __syncthreads();
    if (valid) {
      int st = max(ms, cbeg), en = min(me, cend);
      if (en > st) gather_quad(y1 + qf * 8, list, st - cbeg, en - st, acc);
    }
  }
  int myg = -1;
  if (valid) {
    float d = dinv[node];
#pragma unroll
    for (int k = 0; k < 8; ++k) acc[k] *= d;
    myg = batch[node];
  }
  int g0 = batch[min(b << BSH, N - 1)];
  int g1 = batch[min((b << BSH) + BKTN - 1, N - 1)];
  for (int clo = g0; clo <= g1; clo += 8) {
    for (int j = tid; j < 8 * 32; j += 1024) pool[j] = 0.f;
    __syncthreads();
    if (myg >= clo && myg < clo + 8) {
      float* pp = pool + (myg - clo) * 32 + qf * 8;
#pragma unroll
      for (int k = 0; k < 8; ++k) atomicAdd(pp + k, acc[k]);
    }
    __syncthreads();
    int ng = min(8, g1 - clo + 1);
    for (int j = tid; j < ng * 32; j += 1024)
      atomicAdd(&P[(size_t)(clo + (j >> 5)) * 32 + (j & 31)], pool[j]);
    __syncthreads();
  }
}

// out[g] = P[g] @ W2 + cnt[g]*b2; cnt via binary search on sorted batch
__global__ __launch_bounds__(64) void k_final(const float* __restrict__ P,
                                              const int* __restrict__ batch, int N,
                                              const float* __restrict__ W2,
                                              const float* __restrict__ b2,
                                              float* __restrict__ out) {
  __shared__ float pr[32];
  __shared__ int se[2];
  int g = blockIdx.x, tid = threadIdx.x;
  if (tid < 2) {
    int v = g + tid;
    int lo = 0, hi = N;
    while (lo < hi) {
      int mid = (lo + hi) >> 1;
      if (batch[mid] < v) lo = mid + 1; else hi = mid;
    }
    se[tid] = lo;
  }
  if (tid < 32) pr[tid] = P[(size_t)g * 32 + tid];
  __syncthreads();
  if (tid < 41) {
    float o = (float)(se[1] - se[0]) * b2[tid];
#pragma unroll
    for (int k = 0; k < 32; ++k) o += pr[k] * W2[k * 41 + tid];
    out[(size_t)g * 41 + tid] = o;
  }
}

extern "C" void kernel_launch(void* const* d_in, const int* in_sizes, int n_in,
                              void* d_out, int out_size, void* d_ws, size_t ws_size,
                              hipStream_t stream) {
  const int* x_ids = (const int*)d_in[0];
  const int* edge_index = (const int*)d_in[1];
  const int* batch = (const int*)d_in[2];
  const float* emb = (const float*)d_in[3];
  const float* W1 = (const float*)d_in[4];
  const float* b1 = (const float*)d_in[5];
  const float* W2 = (const float*)d_in[6];
  const float* b2 = (const float*)d_in[7];
  float* out = (float*)d_out;

  const int N = in_sizes[0];
  const int E = in_sizes[1] / 2;
  const int G = out_size / 41;
  const int Nh = N / 2;
  const int* row = edge_index;
  const int* col = edge_index + E;

  const int nbkt = (N + BKTN - 1) >> BSH;       // 391 fine buckets
  int nblk = (E + EPB - 1) / EPB;               // 196
  const int nblkp = (nblk + 7) & ~7;            // 200 (pad for XCD swizzle)

  char* ws = (char*)d_ws;
  size_t woff = 0;
  auto alloc = [&](size_t bytes) -> char* {
    char* p = ws + woff;
    woff += (bytes + 255) & ~(size_t)255;
    return p;
  };
  int* staging = (int*)alloc((size_t)nbkt * CAP * 4);
  int* edge_row = (int*)alloc((size_t)nbkt * CAP * 4);
  int* cp0 = (int*)alloc((size_t)nbkt * BKTN * 4);
  int* cp1 = (int*)alloc((size_t)nbkt * BKTN * 4);
  float* dinv = (float*)alloc((size_t)N * 4);
  unsigned short* ag1 = (unsigned short*)alloc((size_t)N * 16 * 2);
  unsigned short* y1 = (unsigned short*)alloc((size_t)N * 32 * 2);
  int* endp = (int*)alloc((size_t)nbkt * 4);
  // P and cursor contiguous: ONE memset clears both
  float* P = (float*)alloc((size_t)G * 32 * 4 + (size_t)nbkt * 4);
  int* cursor = (int*)(P + (size_t)G * 32);
  (void)ws_size; (void)n_in;

  hipMemsetAsync(P, 0, (size_t)G * 32 * 4 + (size_t)nbkt * 4, stream);

  k_scatter<<<nblkp, 1024, 0, stream>>>(row, col, E, nbkt, nblkp, cursor, staging);
  k_build<<<nbkt, 512, 0, stream>>>(staging, cursor, x_ids, emb, N, Nh, nbkt,
                                    cp0, cp1, endp, dinv, ag1, edge_row);
  k_fuse1<<<nbkt, 512, 0, stream>>>(ag1, edge_row, cp0, cp1, endp, dinv, W1, b1,
                                    N, y1);
  k_fuse2<<<2 * nbkt, 1024, 0, stream>>>(y1, edge_row, cp0, cp1, endp, dinv,
                                         batch, N, Nh, nbkt, P);
  k_final<<<G, 64, 0, stream>>>(P, batch, N, W2, b2, out);
}

// Round 10
// 209.716 us; speedup vs baseline: 1.0448x; 1.0448x over previous
//
#include <hip/hip_runtime.h>

// 2-layer GCN, R22: R20 base + DEPTH-8 gather pipelines (the one untested
// lever from the R17 falsifier list).
//   Experiment record on fuse2 (3.2M random row-visits):
//     R16/R18/R20 quad, HBM/L3-backed: 52.4us  <- best
//     R14/R15/R17/R21 L2-resident variants: 60-70us (residency is NOT the
//     lever; R21 proved it directly: FETCH 85->20MB, time UP 33%)
//   Little's law on R16: ~0.1 visits/cy/CU at ~600cy latency => ~60
//   in-flight/CU, consistent with MLP-limited (8 loads in flight/lane).
//   R22 doubles per-lane depth to 16 in flight (v[8]+w[8] uint4 buffers,
//   VGPR ~80 < 102 spill point; LDS remains the occupancy binder).
//
// Standing lessons: R1/R2 no scattered-4B stores / hot global atomics; R4
// no single-block stages; R6 register accumulation; R10 no cooperative
// launch; R13 atomic segment reservation; R14 occupancy is not the gather
// lever; R15 no dependent load pairs; R16 quad-gather 1 inst/edge is the
// right shape; R17/R21 L2-residency of the plane is NOT the lever; R18
// scatter needs big EPB; R20 edge-stream nt-loads are a no-op.

constexpr int EPB = 16384;         // edges per scatter block
constexpr int BSH = 8;             // 256 nodes per fine bucket
constexpr int BKTN = 1 << BSH;
constexpr int CAP = 10240;         // per-bucket slot capacity (max ~8.6K here)
constexpr int CAPC = 8704;         // fuse LDS window (34KB)

typedef int vint4 __attribute__((ext_vector_type(4)));  // native 16B vector

__device__ inline unsigned short f2bf(float x) {
  unsigned u = __float_as_uint(x);
  u += 0x7FFF + ((u >> 16) & 1);   // round-to-nearest-even
  return (unsigned short)(u >> 16);
}
__device__ inline float bf2f(unsigned short h) {
  return __uint_as_float((unsigned)h << 16);
}
__device__ inline unsigned pk(float a, float b) {
  return (unsigned)f2bf(a) | ((unsigned)f2bf(b) << 16);
}
__device__ __forceinline__ void add8(float* acc, uint4 v) {
  acc[0] += bf2f(v.x & 0xFFFF); acc[1] += bf2f(v.x >> 16);
  acc[2] += bf2f(v.y & 0xFFFF); acc[3] += bf2f(v.y >> 16);
  acc[4] += bf2f(v.z & 0xFFFF); acc[5] += bf2f(v.z >> 16);
  acc[6] += bf2f(v.w & 0xFFFF); acc[7] += bf2f(v.w >> 16);
}

// fuse1 gather: 2 lanes per 32B row, DEPTH-8 two-buffer pipeline
// (16 loads in flight per lane; all indices compile-time -> registers)
__device__ __forceinline__ void gather8(const unsigned short* __restrict__ base,
                                        const int* list, int st, int dg,
                                        float acc[8]) {
  int j = 0;
  if (dg >= 16) {
    uint4 v0, v1, v2, v3, v4, v5, v6, v7;
    v0 = *(const uint4*)(base + (size_t)list[st + 0] * 16);
    v1 = *(const uint4*)(base + (size_t)list[st + 1] * 16);
    v2 = *(const uint4*)(base + (size_t)list[st + 2] * 16);
    v3 = *(const uint4*)(base + (size_t)list[st + 3] * 16);
    v4 = *(const uint4*)(base + (size_t)list[st + 4] * 16);
    v5 = *(const uint4*)(base + (size_t)list[st + 5] * 16);
    v6 = *(const uint4*)(base + (size_t)list[st + 6] * 16);
    v7 = *(const uint4*)(base + (size_t)list[st + 7] * 16);
    for (j = 8; j + 8 <= dg; j += 8) {
      uint4 w0 = *(const uint4*)(base + (size_t)list[st + j + 0] * 16);
      uint4 w1 = *(const uint4*)(base + (size_t)list[st + j + 1] * 16);
      uint4 w2 = *(const uint4*)(base + (size_t)list[st + j + 2] * 16);
      uint4 w3 = *(const uint4*)(base + (size_t)list[st + j + 3] * 16);
      uint4 w4 = *(const uint4*)(base + (size_t)list[st + j + 4] * 16);
      uint4 w5 = *(const uint4*)(base + (size_t)list[st + j + 5] * 16);
      uint4 w6 = *(const uint4*)(base + (size_t)list[st + j + 6] * 16);
      uint4 w7 = *(const uint4*)(base + (size_t)list[st + j + 7] * 16);
      add8(acc, v0); add8(acc, v1); add8(acc, v2); add8(acc, v3);
      add8(acc, v4); add8(acc, v5); add8(acc, v6); add8(acc, v7);
      v0 = w0; v1 = w1; v2 = w2; v3 = w3;
      v4 = w4; v5 = w5; v6 = w6; v7 = w7;
    }
    add8(acc, v0); add8(acc, v1); add8(acc, v2); add8(acc, v3);
    add8(acc, v4); add8(acc, v5); add8(acc, v6); add8(acc, v7);
  }
  for (; j < dg; ++j)
    add8(acc, *(const uint4*)(base + (size_t)list[st + j] * 16));
}

// fuse2 quad gather: 4 lanes cover one 64B y1 row per edge; DEPTH-8
// two-buffer pipeline (16 loads in flight per lane)
__device__ __forceinline__ void gather_quad(const unsigned short* __restrict__ base,
                                            const int* list, int st, int dg,
                                            float acc[8]) {
  int j = 0;
  if (dg >= 16) {
    uint4 v0, v1, v2, v3, v4, v5, v6, v7;
    v0 = *(const uint4*)(base + (size_t)list[st + 0] * 32);
    v1 = *(const uint4*)(base + (size_t)list[st + 1] * 32);
    v2 = *(const uint4*)(base + (size_t)list[st + 2] * 32);
    v3 = *(const uint4*)(base + (size_t)list[st + 3] * 32);
    v4 = *(const uint4*)(base + (size_t)list[st + 4] * 32);
    v5 = *(const uint4*)(base + (size_t)list[st + 5] * 32);
    v6 = *(const uint4*)(base + (size_t)list[st + 6] * 32);
    v7 = *(const uint4*)(base + (size_t)list[st + 7] * 32);
    for (j = 8; j + 8 <= dg; j += 8) {
      uint4 w0 = *(const uint4*)(base + (size_t)list[st + j + 0] * 32);
      uint4 w1 = *(const uint4*)(base + (size_t)list[st + j + 1] * 32);
      uint4 w2 = *(const uint4*)(base + (size_t)list[st + j + 2] * 32);
      uint4 w3 = *(const uint4*)(base + (size_t)list[st + j + 3] * 32);
      uint4 w4 = *(const uint4*)(base + (size_t)list[st + j + 4] * 32);
      uint4 w5 = *(const uint4*)(base + (size_t)list[st + j + 5] * 32);
      uint4 w6 = *(const uint4*)(base + (size_t)list[st + j + 6] * 32);
      uint4 w7 = *(const uint4*)(base + (size_t)list[st + j + 7] * 32);
      add8(acc, v0); add8(acc, v1); add8(acc, v2); add8(acc, v3);
      add8(acc, v4); add8(acc, v5); add8(acc, v6); add8(acc, v7);
      v0 = w0; v1 = w1; v2 = w2; v3 = w3;
      v4 = w4; v5 = w5; v6 = w6; v7 = w7;
    }
    add8(acc, v0); add8(acc, v1); add8(acc, v2); add8(acc, v3);
    add8(acc, v4); add8(acc, v5); add8(acc, v6); add8(acc, v7);
  }
  for (; j < dg; ++j)
    add8(acc, *(const uint4*)(base + (size_t)list[st + j] * 32));
}

// coalesced window copy global->LDS, nt loads (edge list is one-shot)
__device__ __forceinline__ void copy_window(int* list, const int* __restrict__ src,
                                            int n, int tid) {
  const vint4* s4 = (const vint4*)src;
  vint4* d4 = (vint4*)list;
  int n4 = n >> 2;
  for (int i = tid; i < n4; i += 512) d4[i] = __builtin_nontemporal_load(s4 + i);
  for (int i = (n4 << 2) + tid; i < n; i += 512)
    list[i] = __builtin_nontemporal_load(src + i);
}

// XCD swizzle: adjacent edge windows handled by same-XCD blocks (blk%8 heur.)
__device__ __forceinline__ int swz(int b, int nblkp) {
  return (b & 7) * (nblkp >> 3) + (b >> 3);
}

// scatter: in-LDS counting sort of this block's 16K edges; per-bucket
// global segment reserved via ONE atomicAdd on cursor[b]; coalesced flush
// into padded staging[b*CAP + base ...].
__global__ __launch_bounds__(1024) void k_scatter(const int* __restrict__ row,
                                                  const int* __restrict__ col, int E,
                                                  int nbkt, int nblkp,
                                                  int* __restrict__ cursor,
                                                  int* __restrict__ staging) {
  __shared__ int sbuf[EPB];
  __shared__ int cnt[512], sc[512], cur[512], gbase[512];
  int tid = threadIdx.x;
  int lane = tid & 63, wv = tid >> 6;
  int blk = swz(blockIdx.x, nblkp);
  if (tid < 512) cnt[tid] = 0;
  __syncthreads();
  int e0 = blk * EPB, e1 = min(E, e0 + EPB);
  for (int e = e0 + tid; e < e1; e += 1024)
    atomicAdd(&cnt[col[e] >> BSH], 1);
  __syncthreads();
  if (tid < 512) {
    int c = cnt[tid];
    sc[tid] = c;
    gbase[tid] = c ? atomicAdd(&cursor[tid], c) : 0;  // segment reservation
  }
  __syncthreads();
  for (int o = 1; o < 512; o <<= 1) {
    int u = (tid < 512 && tid >= o) ? sc[tid - o] : 0;
    __syncthreads();
    if (tid < 512) sc[tid] += u;
    __syncthreads();
  }
  if (tid < 512) { int st = sc[tid] - cnt[tid]; sc[tid] = st; cur[tid] = st; }
  __syncthreads();
  for (int e = e0 + tid; e < e1; e += 1024) {
    int c = col[e];
    int b = c >> BSH;
    int pos = atomicAdd(&cur[b], 1);
    sbuf[pos] = (row[e] << BSH) | (c & (BKTN - 1));
  }
  __syncthreads();
  for (int b = wv; b < nbkt; b += 16) {
    int lbeg = sc[b], lcnt = cnt[b];
    int gb = gbase[b];
    int lim = CAP - gb;                 // overflow guard (never hit at scale)
    if (lcnt > lim) lcnt = lim > 0 ? lim : 0;
    int g = b * CAP + gb;
    for (int j = lane; j < lcnt; j += 64)
      staging[g + j] = sbuf[lbeg + j];
  }
}

// per fine bucket: LDS count -> col_ptr/endp/dinv + fused emb transform;
// LDS fill sorted-by-node; COALESCED flush to edge_row (padded layout)
__global__ __launch_bounds__(512) void k_build(const int* __restrict__ staging,
                                               const int* __restrict__ cursor,
                                               const int* __restrict__ x_ids,
                                               const float* __restrict__ emb,
                                               int N, int nbkt,
                                               int* __restrict__ col_ptr,
                                               int* __restrict__ endp,
                                               float* __restrict__ dinv,
                                               unsigned short* __restrict__ ag1,
                                               int* __restrict__ edge_row) {
  __shared__ int list[CAP];
  __shared__ int cnt[BKTN], sc[BKTN], lcur[BKTN];
  int tid = threadIdx.x, b = blockIdx.x;
  int beg = b * CAP;
  int total = min(cursor[b], CAP);
  int end = beg + total;
  if (tid < BKTN) cnt[tid] = 0;
  __syncthreads();
  for (int i = beg + tid; i < end; i += 512)
    atomicAdd(&cnt[staging[i] & (BKTN - 1)], 1);
  __syncthreads();
  if (tid < BKTN) sc[tid] = cnt[tid];
  __syncthreads();
  for (int o = 1; o < BKTN; o <<= 1) {
    int u = (tid < BKTN && tid >= o) ? sc[tid - o] : 0;
    __syncthreads();
    if (tid < BKTN) sc[tid] += u;
    __syncthreads();
  }
  if (tid < BKTN) {
    int excl = sc[tid] - cnt[tid];
    sc[tid] = excl;
    lcur[tid] = excl;
    int node = (b << BSH) + tid;
    if (node < N) col_ptr[node] = beg + excl;
  }
  if (tid == 0) {
    endp[b] = end;
    if (b == nbkt - 1) col_ptr[N] = end;
  }
  __syncthreads();
  for (int i = beg + tid; i < end; i += 512) {
    int p = staging[i];
    list[atomicAdd(&lcur[p & (BKTN - 1)], 1)] = p >> BSH;
  }
  __syncthreads();
  for (int i = beg + tid; i < end; i += 512)
    edge_row[i] = list[i - beg];
  // fused embedding transform (cnt intact): 2 lanes/node x 8 feats
  int nloc = tid >> 1, half = tid & 1;
  int node = (b << BSH) + nloc;
  if (node < N) {
    float d = rsqrtf((float)(cnt[nloc] + 1));  // +1 self-loop
    if (half == 0) dinv[node] = d;
    const float* er = emb + (size_t)x_ids[node] * 16 + half * 8;
    float4 e0 = *(const float4*)(er);
    float4 e1 = *(const float4*)(er + 4);
    uint4 o;
    o.x = pk(e0.x * d, e0.y * d); o.y = pk(e0.z * d, e0.w * d);
    o.z = pk(e1.x * d, e1.y * d); o.w = pk(e1.z * d, e1.w * d);
    *(uint4*)(ag1 + (size_t)node * 16 + half * 8) = o;
  }
}

// layer 1: nt window copy -> LDS; depth-8 register gather; fused 16->32
// GEMV/ReLU -> unified y1 [N][32] bf16 (64B rows). 2 lanes/node.
__global__ __launch_bounds__(512) void k_fuse1(const unsigned short* __restrict__ ag1,
                                               const int* __restrict__ edge_row,
                                               const int* __restrict__ col_ptr,
                                               const int* __restrict__ endp,
                                               const float* __restrict__ dinv,
                                               const float* __restrict__ W1,
                                               const float* __restrict__ b1, int N,
                                               unsigned short* __restrict__ y1) {
  __shared__ int list[CAPC];
  __shared__ float W[512];
  __shared__ float bb[32];
  int tid = threadIdx.x, b = blockIdx.x;
  W[tid] = W1[tid];
  if (tid < 32) bb[tid] = b1[tid];
  int nloc = tid >> 1, half = tid & 1;
  int node = (b << BSH) + nloc;
  bool valid = node < N;
  int beg = b * CAP;
  int end = endp[b];
  int ms = 0, me = 0;
  float acc[8];
  if (valid) {
    ms = col_ptr[node];
    me = (nloc == BKTN - 1) ? end : col_ptr[node + 1];
    uint4 v = *(const uint4*)(ag1 + (size_t)node * 16 + half * 8);
    acc[0] = bf2f(v.x & 0xFFFF); acc[1] = bf2f(v.x >> 16);
    acc[2] = bf2f(v.y & 0xFFFF); acc[3] = bf2f(v.y >> 16);
    acc[4] = bf2f(v.z & 0xFFFF); acc[5] = bf2f(v.z >> 16);
    acc[6] = bf2f(v.w & 0xFFFF); acc[7] = bf2f(v.w >> 16);
  } else {
#pragma unroll
    for (int k = 0; k < 8; ++k) acc[k] = 0.f;
  }
  for (int cbeg = beg; cbeg < end; cbeg += CAPC) {
    int cend = min(end, cbeg + CAPC);
    __syncthreads();
    copy_window(list, edge_row + cbeg, cend - cbeg, tid);
    __syncthreads();
    if (valid) {
      int st = max(ms, cbeg), en = min(me, cend);
      if (en > st) gather8(ag1 + half * 8, list, st - cbeg, en - st, acc);
    }
  }
  if (!valid) return;
  float d = dinv[node];
  float sx[8], xo[8];
#pragma unroll
  for (int k = 0; k < 8; ++k) sx[k] = acc[k] * d;
#pragma unroll
  for (int k = 0; k < 8; ++k) xo[k] = __shfl_xor(sx[k], 1);
  float x[16];
  if (half == 0) {
#pragma unroll
    for (int k = 0; k < 8; ++k) { x[k] = sx[k]; x[8 + k] = xo[k]; }
  } else {
#pragma unroll
    for (int k = 0; k < 8; ++k) { x[k] = xo[k]; x[8 + k] = sx[k]; }
  }
  int j0 = half * 16;
  float a[16];
#pragma unroll
  for (int j = 0; j < 16; ++j) a[j] = bb[j0 + j];
#pragma unroll
  for (int k = 0; k < 16; ++k) {
    float xv = x[k];
#pragma unroll
    for (int j = 0; j < 16; ++j) a[j] += xv * W[k * 32 + j0 + j];
  }
#pragma unroll
  for (int j = 0; j < 16; ++j) a[j] = fmaxf(a[j], 0.f) * d;
  uint4 o0 = {pk(a[0], a[1]), pk(a[2], a[3]), pk(a[4], a[5]), pk(a[6], a[7])};
  uint4 o1 = {pk(a[8], a[9]), pk(a[10], a[11]), pk(a[12], a[13]), pk(a[14], a[15])};
  // unified row: y1[node][half*16 .. half*16+15]
  unsigned short* yp = y1 + (size_t)node * 32 + half * 16;
  *(uint4*)(yp) = o0;
  *(uint4*)(yp + 8) = o1;
}

// layer 2: quad-gather. blockIdx -> (bucket, half); 512 thr = 128 nodes x
// 4 lanes; lane qf owns feats qf*8..qf*8+7; one 16B load per edge per lane
// = one line-request per edge per QUAD. Fused sorted-batch pooling ->
// atomicAdd P[G][32].
__global__ __launch_bounds__(512) void k_fuse2(const unsigned short* __restrict__ y1,
                                               const int* __restrict__ edge_row,
                                               const int* __restrict__ col_ptr,
                                               const int* __restrict__ endp,
                                               const float* __restrict__ dinv,
                                               const int* __restrict__ batch,
                                               int N, int nbkt,
                                               float* __restrict__ P) {
  __shared__ int list[CAPC];
  __shared__ float pool[8 * 32];
  int bx = blockIdx.x;
  int b = bx >> 1, np = bx & 1;
  int tid = threadIdx.x;
  int nloc = np * 128 + (tid >> 2), qf = tid & 3;
  int node = (b << BSH) + nloc;
  bool valid = node < N;
  int end = endp[b];
  // this half-block's contiguous edge sub-range (dst-sorted)
  int base0 = (b << BSH) + np * 128;
  int rbeg = col_ptr[min(base0, N)];
  int rend = (np == 1) ? end : col_ptr[min(base0 + 128, N)];
  if (base0 >= N) rbeg = rend;        // fully-invalid half (tail safety)
  int ms = 0, me = 0;
  float acc[8];
  if (valid) {
    ms = col_ptr[node];
    me = (nloc == BKTN - 1) ? end : col_ptr[node + 1];
    // self term: y1[node] chunk
    uint4 v = *(const uint4*)(y1 + (size_t)node * 32 + qf * 8);
    acc[0] = bf2f(v.x & 0xFFFF); acc[1] = bf2f(v.x >> 16);
    acc[2] = bf2f(v.y & 0xFFFF); acc[3] = bf2f(v.y >> 16);
    acc[4] = bf2f(v.z & 0xFFFF); acc[5] = bf2f(v.z >> 16);
    acc[6] = bf2f(v.w & 0xFFFF); acc[7] = bf2f(v.w >> 16);
  } else {
#pragma unroll
    for (int k = 0; k < 8; ++k) acc[k] = 0.f;
  }
  for (int cbeg = rbeg; cbeg < rend; cbeg += CAPC) {
    int cend = min(rend, cbeg + CAPC);
    __syncthreads();
    copy_window(list, edge_row + cbeg, cend - cbeg, tid);
    __syncthreads();
    if (valid) {
      int st = max(ms, cbeg), en = min(me, cend);
      if (en > st) gather_quad(y1 + qf * 8, list, st - cbeg, en - st, acc);
    }
  }
  int myg = -1;
  if (valid) {
    float d = dinv[node];
#pragma unroll
    for (int k = 0; k < 8; ++k) acc[k] *= d;
    myg = batch[node];
  }
  int g0 = batch[min(base0, N - 1)];
  int g1 = batch[min(base0 + 127, N - 1)];
  for (int clo = g0; clo <= g1; clo += 8) {
    for (int j = tid; j < 8 * 32; j += 512) pool[j] = 0.f;
    __syncthreads();
    if (myg >= clo && myg < clo + 8) {
      float* pp = pool + (myg - clo) * 32 + qf * 8;
#pragma unroll
      for (int k = 0; k < 8; ++k) atomicAdd(pp + k, acc[k]);
    }
    __syncthreads();
    int ng = min(8, g1 - clo + 1);
    for (int j = tid; j < ng * 32; j += 512)
      atomicAdd(&P[(size_t)(clo + (j >> 5)) * 32 + (j & 31)], pool[j]);
    __syncthreads();
  }
}

// out[g] = P[g] @ W2 + cnt[g]*b2; cnt via binary search on sorted batch
__global__ __launch_bounds__(64) void k_final(const float* __restrict__ P,
                                              const int* __restrict__ batch, int N,
                                              const float* __restrict__ W2,
                                              const float* __restrict__ b2,
                                              float* __restrict__ out) {
  __shared__ float pr[32];
  __shared__ int se[2];
  int g = blockIdx.x, tid = threadIdx.x;
  if (tid < 2) {
    int v = g + tid;
    int lo = 0, hi = N;
    while (lo < hi) {
      int mid = (lo + hi) >> 1;
      if (batch[mid] < v) lo = mid + 1; else hi = mid;
    }
    se[tid] = lo;
  }
  if (tid < 32) pr[tid] = P[(size_t)g * 32 + tid];
  __syncthreads();
  if (tid < 41) {
    float o = (float)(se[1] - se[0]) * b2[tid];
#pragma unroll
    for (int k = 0; k < 32; ++k) o += pr[k] * W2[k * 41 + tid];
    out[(size_t)g * 41 + tid] = o;
  }
}

extern "C" void kernel_launch(void* const* d_in, const int* in_sizes, int n_in,
                              void* d_out, int out_size, void* d_ws, size_t ws_size,
                              hipStream_t stream) {
  const int* x_ids = (const int*)d_in[0];
  const int* edge_index = (const int*)d_in[1];
  const int* batch = (const int*)d_in[2];
  const float* emb = (const float*)d_in[3];
  const float* W1 = (const float*)d_in[4];
  const float* b1 = (const float*)d_in[5];
  const float* W2 = (const float*)d_in[6];
  const float* b2 = (const float*)d_in[7];
  float* out = (float*)d_out;

  const int N = in_sizes[0];
  const int E = in_sizes[1] / 2;
  const int G = out_size / 41;
  const int* row = edge_index;
  const int* col = edge_index + E;

  const int nbkt = (N + BKTN - 1) >> BSH;       // 391 fine buckets
  int nblk = (E + EPB - 1) / EPB;               // 196
  const int nblkp = (nblk + 7) & ~7;            // 200 (pad for XCD swizzle)

  char* ws = (char*)d_ws;
  size_t woff = 0;
  auto alloc = [&](size_t bytes) -> char* {
    char* p = ws + woff;
    woff += (bytes + 255) & ~(size_t)255;
    return p;
  };
  int* staging = (int*)alloc((size_t)nbkt * CAP * 4);
  int* edge_row = (int*)alloc((size_t)nbkt * CAP * 4);
  int* col_ptr = (int*)alloc(((size_t)N + 1) * 4);
  float* dinv = (float*)alloc((size_t)N * 4);
  unsigned short* ag1 = (unsigned short*)alloc((size_t)N * 16 * 2);
  unsigned short* y1 = (unsigned short*)alloc((size_t)N * 32 * 2);
  int* endp = (int*)alloc((size_t)nbkt * 4);
  // P and cursor contiguous: ONE memset clears both
  float* P = (float*)alloc((size_t)G * 32 * 4 + (size_t)nbkt * 4);
  int* cursor = (int*)(P + (size_t)G * 32);
  (void)ws_size; (void)n_in;

  hipMemsetAsync(P, 0, (size_t)G * 32 * 4 + (size_t)nbkt * 4, stream);

  k_scatter<<<nblkp, 1024, 0, stream>>>(row, col, E, nbkt, nblkp, cursor, staging);
  k_build<<<nbkt, 512, 0, stream>>>(staging, cursor, x_ids, emb, N, nbkt,
                                    col_ptr, endp, dinv, ag1, edge_row);
  k_fuse1<<<nbkt, 512, 0, stream>>>(ag1, edge_row, col_ptr, endp, dinv, W1, b1,
                                    N, y1);
  k_fuse2<<<2 * nbkt, 512, 0, stream>>>(y1, edge_row, col_ptr, endp, dinv,
                                        batch, N, nbkt, P);
  k_final<<<G, 64, 0, stream>>>(P, batch, N, W2, b2, out);
}

// Round 11
// 201.634 us; speedup vs baseline: 1.0867x; 1.0401x over previous
//
#include <hip/hip_runtime.h>

// 2-layer GCN, R23: FINAL — restore the proven-best R16/R20 configuration.
//   fuse2 experiment matrix COMPLETE (all axes lose vs this config):
//     occupancy +45% -> +5% (R14); L2-residency -> 33% SLOWER at equal
//     structure (R21: FETCH 85->20MB, 69.7us); dependent load pairs ->
//     worse (R15); depth-8 pipeline -> worse, occupancy drop (R22);
//     nt edge loads -> null (R20); quad 1-inst/edge -> best (R16).
//   Model: the random 64B-line gather is pinned at ~60K line-visits/us
//   (~1.6-1.7 TB/s L3-side random-line service) — a hardware service-rate
//   roof, insensitive to SIMD-side parallelism. bf16 is the narrowest row
//   the 0.25 absmax budget tolerates (fp8 ~6% rms would blow it); the
//   src-major sum-swap rewrite prices at ~-10us net for +27us of extra
//   sort — rejected at current risk budget.
//
// Standing lessons: R1/R2 no scattered-4B stores / hot global atomics; R4
// no single-block stages; R6 register accumulation; R10 no cooperative
// launch; R13 atomic segment reservation beats hist+scan; R14 occupancy
// is not the gather lever; R15 no dependent load pairs; R16 quad-gather
// is the right shape; R17/R21 L2-residency is not the lever; R18 scatter
// needs big EPB; R20 nt edge loads are a no-op; R22 depth-4 is optimal
// (deeper costs occupancy).

constexpr int EPB = 16384;         // edges per scatter block
constexpr int BSH = 8;             // 256 nodes per fine bucket
constexpr int BKTN = 1 << BSH;
constexpr int CAP = 10240;         // per-bucket slot capacity (max ~8.6K here)
constexpr int CAPC = 8704;         // fuse LDS window (34KB)

typedef int vint4 __attribute__((ext_vector_type(4)));  // native 16B vector

__device__ inline unsigned short f2bf(float x) {
  unsigned u = __float_as_uint(x);
  u += 0x7FFF + ((u >> 16) & 1);   // round-to-nearest-even
  return (unsigned short)(u >> 16);
}
__device__ inline float bf2f(unsigned short h) {
  return __uint_as_float((unsigned)h << 16);
}
__device__ inline unsigned pk(float a, float b) {
  return (unsigned)f2bf(a) | ((unsigned)f2bf(b) << 16);
}
__device__ __forceinline__ void add8(float* acc, uint4 v) {
  acc[0] += bf2f(v.x & 0xFFFF); acc[1] += bf2f(v.x >> 16);
  acc[2] += bf2f(v.y & 0xFFFF); acc[3] += bf2f(v.y >> 16);
  acc[4] += bf2f(v.z & 0xFFFF); acc[5] += bf2f(v.z >> 16);
  acc[6] += bf2f(v.w & 0xFFFF); acc[7] += bf2f(v.w >> 16);
}

// fuse1 gather: 2 lanes per 32B row, depth-4 + prefetch pipeline
__device__ __forceinline__ void gather8(const unsigned short* __restrict__ base,
                                        const int* list, int st, int dg,
                                        float acc[8]) {
  int j = 0;
  if (dg >= 8) {
    int r0 = list[st], r1 = list[st + 1], r2 = list[st + 2], r3 = list[st + 3];
    uint4 v0 = *(const uint4*)(base + (size_t)r0 * 16);
    uint4 v1 = *(const uint4*)(base + (size_t)r1 * 16);
    uint4 v2 = *(const uint4*)(base + (size_t)r2 * 16);
    uint4 v3 = *(const uint4*)(base + (size_t)r3 * 16);
    for (j = 4; j + 4 <= dg; j += 4) {
      int s0 = list[st + j], s1 = list[st + j + 1];
      int s2 = list[st + j + 2], s3 = list[st + j + 3];
      uint4 w0 = *(const uint4*)(base + (size_t)s0 * 16);
      uint4 w1 = *(const uint4*)(base + (size_t)s1 * 16);
      uint4 w2 = *(const uint4*)(base + (size_t)s2 * 16);
      uint4 w3 = *(const uint4*)(base + (size_t)s3 * 16);
      add8(acc, v0); add8(acc, v1); add8(acc, v2); add8(acc, v3);
      v0 = w0; v1 = w1; v2 = w2; v3 = w3;
    }
    add8(acc, v0); add8(acc, v1); add8(acc, v2); add8(acc, v3);
  }
  for (; j < dg; ++j)
    add8(acc, *(const uint4*)(base + (size_t)list[st + j] * 16));
}

// fuse2 quad gather: 4 lanes cover one 64B y1 row per edge (one vmem
// instruction per 16 edges); base pre-offset by qf*8 shorts
__device__ __forceinline__ void gather_quad(const unsigned short* __restrict__ base,
                                            const int* list, int st, int dg,
                                            float acc[8]) {
  int j = 0;
  if (dg >= 8) {
    int r0 = list[st], r1 = list[st + 1], r2 = list[st + 2], r3 = list[st + 3];
    uint4 v0 = *(const uint4*)(base + (size_t)r0 * 32);
    uint4 v1 = *(const uint4*)(base + (size_t)r1 * 32);
    uint4 v2 = *(const uint4*)(base + (size_t)r2 * 32);
    uint4 v3 = *(const uint4*)(base + (size_t)r3 * 32);
    for (j = 4; j + 4 <= dg; j += 4) {
      int s0 = list[st + j], s1 = list[st + j + 1];
      int s2 = list[st + j + 2], s3 = list[st + j + 3];
      uint4 w0 = *(const uint4*)(base + (size_t)s0 * 32);
      uint4 w1 = *(const uint4*)(base + (size_t)s1 * 32);
      uint4 w2 = *(const uint4*)(base + (size_t)s2 * 32);
      uint4 w3 = *(const uint4*)(base + (size_t)s3 * 32);
      add8(acc, v0); add8(acc, v1); add8(acc, v2); add8(acc, v3);
      v0 = w0; v1 = w1; v2 = w2; v3 = w3;
    }
    add8(acc, v0); add8(acc, v1); add8(acc, v2); add8(acc, v3);
  }
  for (; j < dg; ++j)
    add8(acc, *(const uint4*)(base + (size_t)list[st + j] * 32));
}

// coalesced window copy global->LDS, nt loads (edge list is one-shot)
__device__ __forceinline__ void copy_window(int* list, const int* __restrict__ src,
                                            int n, int tid) {
  const vint4* s4 = (const vint4*)src;
  vint4* d4 = (vint4*)list;
  int n4 = n >> 2;
  for (int i = tid; i < n4; i += 512) d4[i] = __builtin_nontemporal_load(s4 + i);
  for (int i = (n4 << 2) + tid; i < n; i += 512)
    list[i] = __builtin_nontemporal_load(src + i);
}

// XCD swizzle: adjacent edge windows handled by same-XCD blocks (blk%8 heur.)
__device__ __forceinline__ int swz(int b, int nblkp) {
  return (b & 7) * (nblkp >> 3) + (b >> 3);
}

// scatter: in-LDS counting sort of this block's 16K edges; per-bucket
// global segment reserved via ONE atomicAdd on cursor[b]; coalesced flush
// into padded staging[b*CAP + base ...].
__global__ __launch_bounds__(1024) void k_scatter(const int* __restrict__ row,
                                                  const int* __restrict__ col, int E,
                                                  int nbkt, int nblkp,
                                                  int* __restrict__ cursor,
                                                  int* __restrict__ staging) {
  __shared__ int sbuf[EPB];
  __shared__ int cnt[512], sc[512], cur[512], gbase[512];
  int tid = threadIdx.x;
  int lane = tid & 63, wv = tid >> 6;
  int blk = swz(blockIdx.x, nblkp);
  if (tid < 512) cnt[tid] = 0;
  __syncthreads();
  int e0 = blk * EPB, e1 = min(E, e0 + EPB);
  for (int e = e0 + tid; e < e1; e += 1024)
    atomicAdd(&cnt[col[e] >> BSH], 1);
  __syncthreads();
  if (tid < 512) {
    int c = cnt[tid];
    sc[tid] = c;
    gbase[tid] = c ? atomicAdd(&cursor[tid], c) : 0;  // segment reservation
  }
  __syncthreads();
  for (int o = 1; o < 512; o <<= 1) {
    int u = (tid < 512 && tid >= o) ? sc[tid - o] : 0;
    __syncthreads();
    if (tid < 512) sc[tid] += u;
    __syncthreads();
  }
  if (tid < 512) { int st = sc[tid] - cnt[tid]; sc[tid] = st; cur[tid] = st; }
  __syncthreads();
  for (int e = e0 + tid; e < e1; e += 1024) {
    int c = col[e];
    int b = c >> BSH;
    int pos = atomicAdd(&cur[b], 1);
    sbuf[pos] = (row[e] << BSH) | (c & (BKTN - 1));
  }
  __syncthreads();
  for (int b = wv; b < nbkt; b += 16) {
    int lbeg = sc[b], lcnt = cnt[b];
    int gb = gbase[b];
    int lim = CAP - gb;                 // overflow guard (never hit at scale)
    if (lcnt > lim) lcnt = lim > 0 ? lim : 0;
    int g = b * CAP + gb;
    for (int j = lane; j < lcnt; j += 64)
      staging[g + j] = sbuf[lbeg + j];
  }
}

// per fine bucket: LDS count -> col_ptr/endp/dinv + fused emb transform;
// LDS fill sorted-by-node; COALESCED flush to edge_row (padded layout)
__global__ __launch_bounds__(512) void k_build(const int* __restrict__ staging,
                                               const int* __restrict__ cursor,
                                               const int* __restrict__ x_ids,
                                               const float* __restrict__ emb,
                                               int N, int nbkt,
                                               int* __restrict__ col_ptr,
                                               int* __restrict__ endp,
                                               float* __restrict__ dinv,
                                               unsigned short* __restrict__ ag1,
                                               int* __restrict__ edge_row) {
  __shared__ int list[CAP];
  __shared__ int cnt[BKTN], sc[BKTN], lcur[BKTN];
  int tid = threadIdx.x, b = blockIdx.x;
  int beg = b * CAP;
  int total = min(cursor[b], CAP);
  int end = beg + total;
  if (tid < BKTN) cnt[tid] = 0;
  __syncthreads();
  for (int i = beg + tid; i < end; i += 512)
    atomicAdd(&cnt[staging[i] & (BKTN - 1)], 1);
  __syncthreads();
  if (tid < BKTN) sc[tid] = cnt[tid];
  __syncthreads();
  for (int o = 1; o < BKTN; o <<= 1) {
    int u = (tid < BKTN && tid >= o) ? sc[tid - o] : 0;
    __syncthreads();
    if (tid < BKTN) sc[tid] += u;
    __syncthreads();
  }
  if (tid < BKTN) {
    int excl = sc[tid] - cnt[tid];
    sc[tid] = excl;
    lcur[tid] = excl;
    int node = (b << BSH) + tid;
    if (node < N) col_ptr[node] = beg + excl;
  }
  if (tid == 0) {
    endp[b] = end;
    if (b == nbkt - 1) col_ptr[N] = end;
  }
  __syncthreads();
  for (int i = beg + tid; i < end; i += 512) {
    int p = staging[i];
    list[atomicAdd(&lcur[p & (BKTN - 1)], 1)] = p >> BSH;
  }
  __syncthreads();
  for (int i = beg + tid; i < end; i += 512)
    edge_row[i] = list[i - beg];
  // fused embedding transform (cnt intact): 2 lanes/node x 8 feats
  int nloc = tid >> 1, half = tid & 1;
  int node = (b << BSH) + nloc;
  if (node < N) {
    float d = rsqrtf((float)(cnt[nloc] + 1));  // +1 self-loop
    if (half == 0) dinv[node] = d;
    const float* er = emb + (size_t)x_ids[node] * 16 + half * 8;
    float4 e0 = *(const float4*)(er);
    float4 e1 = *(const float4*)(er + 4);
    uint4 o;
    o.x = pk(e0.x * d, e0.y * d); o.y = pk(e0.z * d, e0.w * d);
    o.z = pk(e1.x * d, e1.y * d); o.w = pk(e1.z * d, e1.w * d);
    *(uint4*)(ag1 + (size_t)node * 16 + half * 8) = o;
  }
}

// layer 1: nt window copy -> LDS; depth-4 register gather; fused 16->32
// GEMV/ReLU -> unified y1 [N][32] bf16 (64B rows). 2 lanes/node.
__global__ __launch_bounds__(512) void k_fuse1(const unsigned short* __restrict__ ag1,
                                               const int* __restrict__ edge_row,
                                               const int* __restrict__ col_ptr,
                                               const int* __restrict__ endp,
                                               const float* __restrict__ dinv,
                                               const float* __restrict__ W1,
                                               const float* __restrict__ b1, int N,
                                               unsigned short* __restrict__ y1) {
  __shared__ int list[CAPC];
  __shared__ float W[512];
  __shared__ float bb[32];
  int tid = threadIdx.x, b = blockIdx.x;
  W[tid] = W1[tid];
  if (tid < 32) bb[tid] = b1[tid];
  int nloc = tid >> 1, half = tid & 1;
  int node = (b << BSH) + nloc;
  bool valid = node < N;
  int beg = b * CAP;
  int end = endp[b];
  int ms = 0, me = 0;
  float acc[8];
  if (valid) {
    ms = col_ptr[node];
    me = (nloc == BKTN - 1) ? end : col_ptr[node + 1];
    uint4 v = *(const uint4*)(ag1 + (size_t)node * 16 + half * 8);
    acc[0] = bf2f(v.x & 0xFFFF); acc[1] = bf2f(v.x >> 16);
    acc[2] = bf2f(v.y & 0xFFFF); acc[3] = bf2f(v.y >> 16);
    acc[4] = bf2f(v.z & 0xFFFF); acc[5] = bf2f(v.z >> 16);
    acc[6] = bf2f(v.w & 0xFFFF); acc[7] = bf2f(v.w >> 16);
  } else {
#pragma unroll
    for (int k = 0; k < 8; ++k) acc[k] = 0.f;
  }
  for (int cbeg = beg; cbeg < end; cbeg += CAPC) {
    int cend = min(end, cbeg + CAPC);
    __syncthreads();
    copy_window(list, edge_row + cbeg, cend - cbeg, tid);
    __syncthreads();
    if (valid) {
      int st = max(ms, cbeg), en = min(me, cend);
      if (en > st) gather8(ag1 + half * 8, list, st - cbeg, en - st, acc);
    }
  }
  if (!valid) return;
  float d = dinv[node];
  float sx[8], xo[8];
#pragma unroll
  for (int k = 0; k < 8; ++k) sx[k] = acc[k] * d;
#pragma unroll
  for (int k = 0; k < 8; ++k) xo[k] = __shfl_xor(sx[k], 1);
  float x[16];
  if (half == 0) {
#pragma unroll
    for (int k = 0; k < 8; ++k) { x[k] = sx[k]; x[8 + k] = xo[k]; }
  } else {
#pragma unroll
    for (int k = 0; k < 8; ++k) { x[k] = xo[k]; x[8 + k] = sx[k]; }
  }
  int j0 = half * 16;
  float a[16];
#pragma unroll
  for (int j = 0; j < 16; ++j) a[j] = bb[j0 + j];
#pragma unroll
  for (int k = 0; k < 16; ++k) {
    float xv = x[k];
#pragma unroll
    for (int j = 0; j < 16; ++j) a[j] += xv * W[k * 32 + j0 + j];
  }
#pragma unroll
  for (int j = 0; j < 16; ++j) a[j] = fmaxf(a[j], 0.f) * d;
  uint4 o0 = {pk(a[0], a[1]), pk(a[2], a[3]), pk(a[4], a[5]), pk(a[6], a[7])};
  uint4 o1 = {pk(a[8], a[9]), pk(a[10], a[11]), pk(a[12], a[13]), pk(a[14], a[15])};
  // unified row: y1[node][half*16 .. half*16+15]
  unsigned short* yp = y1 + (size_t)node * 32 + half * 16;
  *(uint4*)(yp) = o0;
  *(uint4*)(yp + 8) = o1;
}

// layer 2: quad-gather. blockIdx -> (bucket, half); 512 thr = 128 nodes x
// 4 lanes; lane qf owns feats qf*8..qf*8+7; one 16B load per edge per lane
// = one line-request per edge per QUAD. Fused sorted-batch pooling ->
// atomicAdd P[G][32].
__global__ __launch_bounds__(512) void k_fuse2(const unsigned short* __restrict__ y1,
                                               const int* __restrict__ edge_row,
                                               const int* __restrict__ col_ptr,
                                               const int* __restrict__ endp,
                                               const float* __restrict__ dinv,
                                               const int* __restrict__ batch,
                                               int N, int nbkt,
                                               float* __restrict__ P) {
  __shared__ int list[CAPC];
  __shared__ float pool[8 * 32];
  int bx = blockIdx.x;
  int b = bx >> 1, np = bx & 1;
  int tid = threadIdx.x;
  int nloc = np * 128 + (tid >> 2), qf = tid & 3;
  int node = (b << BSH) + nloc;
  bool valid = node < N;
  int end = endp[b];
  // this half-block's contiguous edge sub-range (dst-sorted)
  int base0 = (b << BSH) + np * 128;
  int rbeg = col_ptr[min(base0, N)];
  int rend = (np == 1) ? end : col_ptr[min(base0 + 128, N)];
  if (base0 >= N) rbeg = rend;        // fully-invalid half (tail safety)
  int ms = 0, me = 0;
  float acc[8];
  if (valid) {
    ms = col_ptr[node];
    me = (nloc == BKTN - 1) ? end : col_ptr[node + 1];
    // self term: y1[node] chunk
    uint4 v = *(const uint4*)(y1 + (size_t)node * 32 + qf * 8);
    acc[0] = bf2f(v.x & 0xFFFF); acc[1] = bf2f(v.x >> 16);
    acc[2] = bf2f(v.y & 0xFFFF); acc[3] = bf2f(v.y >> 16);
    acc[4] = bf2f(v.z & 0xFFFF); acc[5] = bf2f(v.z >> 16);
    acc[6] = bf2f(v.w & 0xFFFF); acc[7] = bf2f(v.w >> 16);
  } else {
#pragma unroll
    for (int k = 0; k < 8; ++k) acc[k] = 0.f;
  }
  for (int cbeg = rbeg; cbeg < rend; cbeg += CAPC) {
    int cend = min(rend, cbeg + CAPC);
    __syncthreads();
    copy_window(list, edge_row + cbeg, cend - cbeg, tid);
    __syncthreads();
    if (valid) {
      int st = max(ms, cbeg), en = min(me, cend);
      if (en > st) gather_quad(y1 + qf * 8, list, st - cbeg, en - st, acc);
    }
  }
  int myg = -1;
  if (valid) {
    float d = dinv[node];
#pragma unroll
    for (int k = 0; k < 8; ++k) acc[k] *= d;
    myg = batch[node];
  }
  int g0 = batch[min(base0, N - 1)];
  int g1 = batch[min(base0 + 127, N - 1)];
  for (int clo = g0; clo <= g1; clo += 8) {
    for (int j = tid; j < 8 * 32; j += 512) pool[j] = 0.f;
    __syncthreads();
    if (myg >= clo && myg < clo + 8) {
      float* pp = pool + (myg - clo) * 32 + qf * 8;
#pragma unroll
      for (int k = 0; k < 8; ++k) atomicAdd(pp + k, acc[k]);
    }
    __syncthreads();
    int ng = min(8, g1 - clo + 1);
    for (int j = tid; j < ng * 32; j += 512)
      atomicAdd(&P[(size_t)(clo + (j >> 5)) * 32 + (j & 31)], pool[j]);
    __syncthreads();
  }
}

// out[g] = P[g] @ W2 + cnt[g]*b2; cnt via binary search on sorted batch
__global__ __launch_bounds__(64) void k_final(const float* __restrict__ P,
                                              const int* __restrict__ batch, int N,
                                              const float* __restrict__ W2,
                                              const float* __restrict__ b2,
                                              float* __restrict__ out) {
  __shared__ float pr[32];
  __shared__ int se[2];
  int g = blockIdx.x, tid = threadIdx.x;
  if (tid < 2) {
    int v = g + tid;
    int lo = 0, hi = N;
    while (lo < hi) {
      int mid = (lo + hi) >> 1;
      if (batch[mid] < v) lo = mid + 1; else hi = mid;
    }
    se[tid] = lo;
  }
  if (tid < 32) pr[tid] = P[(size_t)g * 32 + tid];
  __syncthreads();
  if (tid < 41) {
    float o = (float)(se[1] - se[0]) * b2[tid];
#pragma unroll
    for (int k = 0; k < 32; ++k) o += pr[k] * W2[k * 41 + tid];
    out[(size_t)g * 41 + tid] = o;
  }
}

extern "C" void kernel_launch(void* const* d_in, const int* in_sizes, int n_in,
                              void* d_out, int out_size, void* d_ws, size_t ws_size,
                              hipStream_t stream) {
  const int* x_ids = (const int*)d_in[0];
  const int* edge_index = (const int*)d_in[1];
  const int* batch = (const int*)d_in[2];
  const float* emb = (const float*)d_in[3];
  const float* W1 = (const float*)d_in[4];
  const float* b1 = (const float*)d_in[5];
  const float* W2 = (const float*)d_in[6];
  const float* b2 = (const float*)d_in[7];
  float* out = (float*)d_out;

  const int N = in_sizes[0];
  const int E = in_sizes[1] / 2;
  const int G = out_size / 41;
  const int* row = edge_index;
  const int* col = edge_index + E;

  const int nbkt = (N + BKTN - 1) >> BSH;       // 391 fine buckets
  int nblk = (E + EPB - 1) / EPB;               // 196
  const int nblkp = (nblk + 7) & ~7;            // 200 (pad for XCD swizzle)

  char* ws = (char*)d_ws;
  size_t woff = 0;
  auto alloc = [&](size_t bytes) -> char* {
    char* p = ws + woff;
    woff += (bytes + 255) & ~(size_t)255;
    return p;
  };
  int* staging = (int*)alloc((size_t)nbkt * CAP * 4);
  int* edge_row = (int*)alloc((size_t)nbkt * CAP * 4);
  int* col_ptr = (int*)alloc(((size_t)N + 1) * 4);
  float* dinv = (float*)alloc((size_t)N * 4);
  unsigned short* ag1 = (unsigned short*)alloc((size_t)N * 16 * 2);
  unsigned short* y1 = (unsigned short*)alloc((size_t)N * 32 * 2);
  int* endp = (int*)alloc((size_t)nbkt * 4);
  // P and cursor contiguous: ONE memset clears both
  float* P = (float*)alloc((size_t)G * 32 * 4 + (size_t)nbkt * 4);
  int* cursor = (int*)(P + (size_t)G * 32);
  (void)ws_size; (void)n_in;

  hipMemsetAsync(P, 0, (size_t)G * 32 * 4 + (size_t)nbkt * 4, stream);

  k_scatter<<<nblkp, 1024, 0, stream>>>(row, col, E, nbkt, nblkp, cursor, staging);
  k_build<<<nbkt, 512, 0, stream>>>(staging, cursor, x_ids, emb, N, nbkt,
                                    col_ptr, endp, dinv, ag1, edge_row);
  k_fuse1<<<nbkt, 512, 0, stream>>>(ag1, edge_row, col_ptr, endp, dinv, W1, b1,
                                    N, y1);
  k_fuse2<<<2 * nbkt, 512, 0, stream>>>(y1, edge_row, col_ptr, endp, dinv,
                                        batch, N, nbkt, P);
  k_final<<<G, 64, 0, stream>>>(P, batch, N, W2, b2, out);
}